// Round 25
// baseline (265.941 us; speedup 1.0000x reference)
//
#include <hip/hip_runtime.h>
#include <hip/hip_bf16.h>

#define M_DIM 16384
#define K_DIM 1024
#define G_DIM 8
#define N_DIM 2048

#define BM 128
#define BN 128
#define BK 32
#define MT_PER_E 128

typedef short bf16x8 __attribute__((ext_vector_type(8)));
typedef float f32x4 __attribute__((ext_vector_type(4)));
typedef uint u32x4 __attribute__((ext_vector_type(4)));

__device__ int g_bins[32];   // [0..8) counts, [8..17) offsets, [17..25) cursors
__device__ int g_perm[M_DIM];

__global__ void zero_kernel() {
    if (threadIdx.x < 32) g_bins[threadIdx.x] = 0;
}

__global__ void hist_kernel(const int* __restrict__ mi) {
    int m = blockIdx.x * blockDim.x + threadIdx.x;
    if (m < M_DIM) {
        int g = mi[m];
        if (g < 0 || g >= G_DIM) g = 0;
        atomicAdd(&g_bins[g], 1);
    }
}

__global__ void scan_kernel() {
    if (threadIdx.x == 0 && blockIdx.x == 0) {
        int off = 0; g_bins[8] = 0;
        #pragma unroll
        for (int e = 0; e < G_DIM; ++e) { off += g_bins[e]; g_bins[9 + e] = off; }
        #pragma unroll
        for (int e = 0; e < G_DIM; ++e) g_bins[17 + e] = g_bins[8 + e];
    }
}

__global__ void scatter_kernel(const int* __restrict__ mi) {
    int m = blockIdx.x * blockDim.x + threadIdx.x;
    if (m < M_DIM) {
        int g = mi[m];
        if (g < 0 || g >= G_DIM) g = 0;
        int p = atomicAdd(&g_bins[17 + g], 1);
        g_perm[p] = m;
    }
}

// pack two bf16-exact f32 into one u32 (lo in low half) — 1 v_perm_b32
__device__ __forceinline__ uint pkbf(float lo, float hi) {
#if __has_builtin(__builtin_amdgcn_perm)
    return __builtin_amdgcn_perm(__float_as_uint(hi), __float_as_uint(lo), 0x07060302u);
#else
    return (__float_as_uint(lo) >> 16) | (__float_as_uint(hi) & 0xffff0000u);
#endif
}

__device__ __forceinline__ u32x4 pack8(f32x4 l, f32x4 h) {
    u32x4 o;
    o[0] = pkbf(l[0], l[1]);
    o[1] = pkbf(l[2], l[3]);
    o[2] = pkbf(h[0], h[1]);
    o[3] = pkbf(h[2], h[3]);
    return o;
}

__global__ __launch_bounds__(256) void gemm_kernel(
    const float* __restrict__ lhs,   // [M,K] f32 (bf16-exact values)
    const float* __restrict__ rhs,   // [G,N,K] f32
    float* __restrict__ out)         // [M,N] f32
{
    const int e    = blockIdx.y >> 7;
    const int tile = blockIdx.y & 127;
    const int row_start = g_bins[8 + e] + tile * BM;
    const int row_end   = g_bins[9 + e];
    if (row_start >= row_end) return;
    const int valid = min(BM, row_end - row_start);
    const int bn = blockIdx.x * BN;

    __shared__ ushort lsA[BM * BK];  // 8 KiB bf16, XOR-swizzled layout
    __shared__ ushort lsB[BN * BK];  // 8 KiB
    __shared__ int prow[BM];

    const int t = threadIdx.x;
    if (t < BM) prow[t] = (t < valid) ? g_perm[row_start + t] : g_perm[row_start];
    __syncthreads();

    // Staging: thread t covers local row t>>2 (and +64), k-chunk (t&3)*8
    const int srow  = t >> 2;
    const int skoff = (t & 3) * 8;
    const float* a0 = lhs + (size_t)prow[srow] * K_DIM + skoff;
    const float* a1 = lhs + (size_t)prow[64 + srow] * K_DIM + skoff;
    const float* rhs_e = rhs + (size_t)e * N_DIM * K_DIM;
    const float* b0 = rhs_e + (size_t)(bn + srow) * K_DIM + skoff;
    const float* b1 = rhs_e + (size_t)(bn + 64 + srow) * K_DIM + skoff;

    // Swizzled LDS write addresses: byte = (row*64 + slot*16) ^ ((row&7)<<4)
    const int wswz = (t * 16) ^ ((srow & 7) << 4);
    char* const wA0 = (char*)lsA + wswz;
    char* const wA1 = (char*)lsA + wswz + 4096;   // row+64: same (row&7)
    char* const wB0 = (char*)lsB + wswz;
    char* const wB1 = (char*)lsB + wswz + 4096;

    const int lane = t & 63;
    const int wave = t >> 6;
    const int wr = wave >> 1;  // 0..1
    const int wc = wave & 1;   // 0..1
    const int lr = lane & 15;
    const int g16 = (lane >> 4) * 16;     // k-slot byte offset
    const int rswz = (lr & 7) << 4;       // read-side swizzle (row&7 == lr&7)

    f32x4 acc[4][4] = {};

#define LOAD_STAGE(S, off) { \
    S##a0l = *(const f32x4*)(a0 + (off)); S##a0h = *(const f32x4*)(a0 + (off) + 4); \
    S##a1l = *(const f32x4*)(a1 + (off)); S##a1h = *(const f32x4*)(a1 + (off) + 4); \
    S##b0l = *(const f32x4*)(b0 + (off)); S##b0h = *(const f32x4*)(b0 + (off) + 4); \
    S##b1l = *(const f32x4*)(b1 + (off)); S##b1h = *(const f32x4*)(b1 + (off) + 4); }

#define COMMIT_STAGE(S) { \
    *(u32x4*)wA0 = pack8(S##a0l, S##a0h); \
    *(u32x4*)wA1 = pack8(S##a1l, S##a1h); \
    *(u32x4*)wB0 = pack8(S##b0l, S##b0h); \
    *(u32x4*)wB1 = pack8(S##b1l, S##b1h); \
    __syncthreads(); \
    bf16x8 af0 = *(const bf16x8*)((const char*)lsA + (((wr*64 +  0 + lr)*64 + g16) ^ rswz)); \
    bf16x8 af1 = *(const bf16x8*)((const char*)lsA + (((wr*64 + 16 + lr)*64 + g16) ^ rswz)); \
    bf16x8 af2 = *(const bf16x8*)((const char*)lsA + (((wr*64 + 32 + lr)*64 + g16) ^ rswz)); \
    bf16x8 af3 = *(const bf16x8*)((const char*)lsA + (((wr*64 + 48 + lr)*64 + g16) ^ rswz)); \
    bf16x8 bf0 = *(const bf16x8*)((const char*)lsB + (((wc*64 +  0 + lr)*64 + g16) ^ rswz)); \
    bf16x8 bf1 = *(const bf16x8*)((const char*)lsB + (((wc*64 + 16 + lr)*64 + g16) ^ rswz)); \
    bf16x8 bf2 = *(const bf16x8*)((const char*)lsB + (((wc*64 + 32 + lr)*64 + g16) ^ rswz)); \
    bf16x8 bf3 = *(const bf16x8*)((const char*)lsB + (((wc*64 + 48 + lr)*64 + g16) ^ rswz)); \
    acc[0][0] = __builtin_amdgcn_mfma_f32_16x16x32_bf16(af0, bf0, acc[0][0], 0,0,0); \
    acc[0][1] = __builtin_amdgcn_mfma_f32_16x16x32_bf16(af0, bf1, acc[0][1], 0,0,0); \
    acc[0][2] = __builtin_amdgcn_mfma_f32_16x16x32_bf16(af0, bf2, acc[0][2], 0,0,0); \
    acc[0][3] = __builtin_amdgcn_mfma_f32_16x16x32_bf16(af0, bf3, acc[0][3], 0,0,0); \
    acc[1][0] = __builtin_amdgcn_mfma_f32_16x16x32_bf16(af1, bf0, acc[1][0], 0,0,0); \
    acc[1][1] = __builtin_amdgcn_mfma_f32_16x16x32_bf16(af1, bf1, acc[1][1], 0,0,0); \
    acc[1][2] = __builtin_amdgcn_mfma_f32_16x16x32_bf16(af1, bf2, acc[1][2], 0,0,0); \
    acc[1][3] = __builtin_amdgcn_mfma_f32_16x16x32_bf16(af1, bf3, acc[1][3], 0,0,0); \
    acc[2][0] = __builtin_amdgcn_mfma_f32_16x16x32_bf16(af2, bf0, acc[2][0], 0,0,0); \
    acc[2][1] = __builtin_amdgcn_mfma_f32_16x16x32_bf16(af2, bf1, acc[2][1], 0,0,0); \
    acc[2][2] = __builtin_amdgcn_mfma_f32_16x16x32_bf16(af2, bf2, acc[2][2], 0,0,0); \
    acc[2][3] = __builtin_amdgcn_mfma_f32_16x16x32_bf16(af2, bf3, acc[2][3], 0,0,0); \
    acc[3][0] = __builtin_amdgcn_mfma_f32_16x16x32_bf16(af3, bf0, acc[3][0], 0,0,0); \
    acc[3][1] = __builtin_amdgcn_mfma_f32_16x16x32_bf16(af3, bf1, acc[3][1], 0,0,0); \
    acc[3][2] = __builtin_amdgcn_mfma_f32_16x16x32_bf16(af3, bf2, acc[3][2], 0,0,0); \
    acc[3][3] = __builtin_amdgcn_mfma_f32_16x16x32_bf16(af3, bf3, acc[3][3], 0,0,0); \
    __syncthreads(); }

    // Ping-pong pipeline: loads for next K-step issue before current MFMA.
    f32x4 Xa0l,Xa0h,Xa1l,Xa1h,Xb0l,Xb0h,Xb1l,Xb1h;
    f32x4 Ya0l,Ya0h,Ya1l,Ya1h,Yb0l,Yb0h,Yb1l,Yb1h;

    LOAD_STAGE(X, 0)
    for (int k0 = 0; k0 < K_DIM; k0 += 2 * BK) {
        LOAD_STAGE(Y, k0 + BK)
        COMMIT_STAGE(X)
        if (k0 + 2 * BK < K_DIM) LOAD_STAGE(X, k0 + 2 * BK)
        COMMIT_STAGE(Y)
    }
#undef LOAD_STAGE
#undef COMMIT_STAGE

    // Epilogue: C/D layout col=lane&15, row=(lane>>4)*4+j; f32 stores
    #pragma unroll
    for (int m = 0; m < 4; ++m) {
        #pragma unroll
        for (int j = 0; j < 4; ++j) {
            int lrow = wr * 64 + m * 16 + (lane >> 4) * 4 + j;
            if (lrow < valid) {
                size_t grow = (size_t)prow[lrow];
                #pragma unroll
                for (int n = 0; n < 4; ++n) {
                    int gcol = bn + wc * 64 + n * 16 + (lane & 15);
                    out[grow * N_DIM + gcol] = acc[m][n][j];
                }
            }
        }
    }
}

extern "C" void kernel_launch(void* const* d_in, const int* in_sizes, int n_in,
                              void* d_out, int out_size, void* d_ws, size_t ws_size,
                              hipStream_t stream) {
    const float* lhs = (const float*)d_in[0];
    const float* rhs = (const float*)d_in[1];
    const int* mi = (const int*)d_in[2];
    float* out = (float*)d_out;

    zero_kernel<<<1, 64, 0, stream>>>();
    hist_kernel<<<(M_DIM + 255) / 256, 256, 0, stream>>>(mi);
    scan_kernel<<<1, 64, 0, stream>>>();
    scatter_kernel<<<(M_DIM + 255) / 256, 256, 0, stream>>>(mi);

    dim3 grid(N_DIM / BN, G_DIM * MT_PER_E);
    gemm_kernel<<<grid, 256, 0, stream>>>(lhs, rhs, out);
}